// Round 25
// baseline (168.156 us; speedup 1.0000x reference)
//
#include <hip/hip_runtime.h>

#define DEV __device__ __forceinline__

typedef unsigned short bhalf;
typedef __attribute__((ext_vector_type(8))) short bf8v;
typedef __attribute__((ext_vector_type(4))) float f4;
typedef __attribute__((ext_vector_type(4))) unsigned short us4;

namespace {
constexpr int TPB = 256;
constexpr float ATT_SCALE = 0.08838834764831845f; // 1/sqrt(128)

// ---- workspace byte offsets ----
constexpr size_t O_PT  = 0;          // bf16 [640][64][256]  modalities, zero-pad rows
constexpr size_t O_WTS = 20971520;   // bf16 transposed weights (see W_* below)
constexpr size_t O_K1B = 21626880;   // bf16 [128][64][128]
constexpr size_t O_FW  = 23724032;   // bf16 fused weights: VQ[128][256], VK[128][256], VW[256][256]
constexpr size_t O_VQT = 27918336;   // bf16 [128][128][64]  (v1@arm_q)^T
constexpr size_t O_VKT = 30015488;   // bf16 [128][128][64]
constexpr size_t O_G   = 32112640;   // f32  [256][256]  arm_v@epw (consumed by wf2)
constexpr size_t O_VWT = 36306944;   // bf16 [128][256][64]  (vt@epw)^T
constexpr size_t O_Q2B = 40501248;   // bf16 [640][64][128]  (kv1 writes q1 here; s1ker overwrites with q2)
constexpr size_t O_K2B = 50987008;   // bf16 [640][64][128]
constexpr size_t O_W2T = 61472768;   // bf16 [640][256][64]
constexpr size_t O_FV  = 82444288;   // f32  [640][256]  node features X (ORIGINAL; never updated)
constexpr size_t O_HWS = 83099648;   // f32  [3200][256]
constexpr size_t O_EDG = 86376448;   // f32  [3200][256]
constexpr size_t O_XA  = 89654272;
constexpr size_t O_XB  = 90309632;
constexpr size_t O_XU  = 90964992;
constexpr size_t O_XV  = 91620352;
constexpr size_t O_EE  = 92275712;   // reused as XN1 (L1 node pre-BN)
constexpr size_t O_ET  = 95552512;
constexpr size_t O_XN  = 98829312;   // XN0 (L0 node pre-BN)
// regions for MFMA GNN projections
constexpr size_t O_GWT = 99484672;   // bf16 10x[256][256] GNN weights Wt[n][k], order {A,B,U,V,E}xL
constexpr size_t O_CSE = 100795392;  // f32 [256] colsum of E1
constexpr size_t O_FVB = 100796416;  // bf16 [640][256] node features (original, bf16)
constexpr size_t O_HWB = 101124096;  // bf16 [3200][256] raw HWS
constexpr size_t O_EDB = 102762496;  // bf16 [3200][256] edge features after L0
constexpr size_t O_ST2 = 104400896;  // f32 [2560] stat shards (no longer aliases G)

// WTS element offsets (bf16 elems), all stored as Wt[n][k=256]
constexpr size_t W_FAMQ = 0, W_FAMK = 32768, W_ARMQ = 65536, W_ARMK = 98304,
                 W_FAMV = 131072, W_ARMV = 196608, W_EPW = 262144;
// FW element offsets
constexpr size_t FW_VQ = 0, FW_VK = 32768, FW_VW = 65536;

// ST2 stat-shard float offsets (slot = xcd*32 + idx, xcd<8)
constexpr int ST_GS1 = 0, ST_GS2 = 256;
} // namespace

// ---------- helpers ----------

DEV bhalf f2b(float f) {
  unsigned u = __float_as_uint(f);
  return (bhalf)((u + 0x7FFFu + ((u >> 16) & 1u)) >> 16);
}

DEV f4 mfma16(bf8v a, bf8v b, f4 c) {
  return __builtin_amdgcn_mfma_f32_16x16x32_bf16(a, b, c, 0, 0, 0);
}

// fragment load: lane l reads row (r0 + (l&15)), 8 contiguous k at k0 + (l>>4)*8
DEV bf8v ldfrag(const bhalf* base, int r0, int k0, int S, int l) {
  return *reinterpret_cast<const bf8v*>(base + (size_t)(r0 + (l & 15)) * S + k0 + ((l >> 4) << 3));
}

// swizzled LDS fragment load: byte = row*stride + koffB, XOR'd with ((row&7)<<4)
DEV bf8v ldswz(const bhalf* base, int row, int koffB, int strideB) {
  int byte = row * strideB + koffB;
  byte ^= ((row & 7) << 4);
  return *reinterpret_cast<const bf8v*>(reinterpret_cast<const char*>(base) + byte);
}

// sum the 8 per-XCD shards of one stat
DEV float sumShards(const float* base, int idx) {
  float s = 0.f;
  #pragma unroll
  for (int x = 0; x < 8; ++x) s += base[x*32 + idx];
  return s;
}

// in-register row softmax: sv[nt][reg], row per reg spans cols nt*16+(l&15) across 16 lanes
DEV void regSoftmax(float sv[4][4]) {
  #pragma unroll
  for (int reg = 0; reg < 4; ++reg) {
    float m = fmaxf(fmaxf(sv[0][reg], sv[1][reg]), fmaxf(sv[2][reg], sv[3][reg]));
    #pragma unroll
    for (int off = 1; off <= 8; off <<= 1) m = fmaxf(m, __shfl_xor(m, off));
    float s = 0.f;
    #pragma unroll
    for (int nt = 0; nt < 4; ++nt) { float e = __expf(sv[nt][reg] - m); sv[nt][reg] = e; s += e; }
    #pragma unroll
    for (int off = 1; off <= 8; off <<= 1) s += __shfl_xor(s, off);
    float inv = 1.f / s;
    #pragma unroll
    for (int nt = 0; nt < 4; ++nt) sv[nt][reg] *= inv;
  }
}

// ga/gb already point at the per-XCD shard slot
DEV void reduce2Atomic(float a, float b, float* ga, float* gb, float* red) {
  #pragma unroll
  for (int off = 32; off; off >>= 1) { a += __shfl_down(a, off); b += __shfl_down(b, off); }
  if ((threadIdx.x & 63) == 0) { int w = threadIdx.x >> 6; red[w*2] = a; red[w*2+1] = b; }
  __syncthreads();
  if (threadIdx.x == 0) {
    atomicAdd(ga, red[0]+red[2]+red[4]+red[6]);
    atomicAdd(gb, red[1]+red[3]+red[5]+red[7]);
  }
  __syncthreads();
}

// ---------- prep kernel (wprep + modprep + G + GNN weight transpose + colsumE1
//            + ST2 zero + wf2's input-only VQ/VK half) ----------

__global__ void __launch_bounds__(256) prepAll(const float* fq, const float* fk, const float* fv,
                                               const float* aq, const float* ak, const float* av,
                                               const float* ep, bhalf* WT,
                                               const float* af, const float* ef, const float* gf,
                                               const float* attf, const float* sf,
                                               bhalf* PT, float* FV, float* G,
                                               const float* A1, const float* B1, const float* U1,
                                               const float* V1, const float* E1,
                                               const float* A2, const float* B2, const float* U2,
                                               const float* V2, const float* E2,
                                               bhalf* GWT, float* CSE, bhalf* FVB,
                                               bhalf* FW, float* ST2) {
  __shared__ float lb[49*260];
  int tid = threadIdx.x;
  if (blockIdx.x < 1280) {
    // ---- wprep: transpose 7 weight matrices to bf16 Wt[n][256] ----
    int blk = blockIdx.x;
    const float* src; bhalf* dst; int N, n;
    if (blk < 512) {
      int m = blk >> 7; n = blk & 127; N = 128;
      src = (m==0)?fq:(m==1)?fk:(m==2)?aq:ak;
      dst = WT + (size_t)m*32768;
    } else {
      int r = blk - 512; int m = r >> 8; n = r & 255; N = 256;
      src = (m==0)?fv:(m==1)?av:ep;
      dst = WT + 131072 + (size_t)m*65536;
    }
    dst[(size_t)n*256 + tid] = f2b(src[(size_t)tid*N + n]);
  } else if (blockIdx.x < 1920) {
    // ---- modprep: per (bt,u) modality transpose + fv means ----
    int blk = blockIdx.x - 1280;
    int u = blk % 5, bt = blk / 5, b = bt >> 4, t = bt & 15;
    const float* src = (u==0)?af:(u==1)?ef:(u==2)?gf:(u==3)?attf:sf;
    src += ((size_t)b*256*16 + t)*49;
    for (int o = tid; o < 49*256; o += TPB) {
      int c = o / 49, p = o % 49;
      lb[p*260 + c] = src[(size_t)c*784 + p];
    }
    __syncthreads();
    bhalf* pt = PT + (size_t)blk*16384;
    for (int p = 0; p < 64; ++p)
      pt[p*256 + tid] = (p < 49) ? f2b(lb[p*260 + tid]) : (bhalf)0;
    float s = 0.f;
    for (int p = 0; p < 49; ++p) s += lb[p*260 + tid];
    float mval = s * (1.f/49.f);
    size_t idx = (((size_t)(b*5+u)*16) + t)*256 + tid;
    FV[idx] = mval;
    FVB[idx] = f2b(mval);
  } else if (blockIdx.x < 2176) {
    // ---- G = arm_v @ epw (f32), row c per block ----
    int c = blockIdx.x - 1920;
    const float* ar = av + (size_t)c*256;
    float acc = 0.f;
    for (int d = 0; d < 256; ++d)
      acc = fmaf(ar[d], ep[(size_t)d*256 + tid], acc);
    G[(size_t)c*256 + tid] = acc;
  } else if (blockIdx.x < 4736) {
    // ---- GNN weight transpose: 10 x [256][256] f32 -> bf16 Wt[n][256] ----
    int blk = blockIdx.x - 2176;
    int m = blk >> 8, n = blk & 255;
    const float* src = (m==0)?A1:(m==1)?B1:(m==2)?U1:(m==3)?V1:(m==4)?E1:
                       (m==5)?A2:(m==6)?B2:(m==7)?U2:(m==8)?V2:E2;
    GWT[(size_t)m*65536 + (size_t)n*256 + tid] = f2b(src[(size_t)tid*256 + n]);
  } else if (blockIdx.x == 4736) {
    // ---- colsum of E1 + zero the stat-shard region ----
    float s = 0.f;
    for (int c = 0; c < 256; ++c) s += E1[(size_t)c*256 + tid];
    CSE[tid] = s;
    for (int o = tid; o < 2560; o += TPB) ST2[o] = 0.f;
  } else {
    // ---- wf2 input-only half: W_VQ/W_VK (no dependency on G) ----
    int k = blockIdx.x - 4737;
    if (tid < 128) {
      float a1 = 0.f, a2 = 0.f;
      for (int c = 0; c < 256; ++c) {
        float f = fv[(size_t)k*256 + c];
        a1 = fmaf(f, aq[(size_t)c*128 + tid], a1);
        a2 = fmaf(f, ak[(size_t)c*128 + tid], a2);
      }
      FW[FW_VQ + (size_t)tid*256 + k] = f2b(a1);
      FW[FW_VK + (size_t)tid*256 + k] = f2b(a2);
    }
  }
}

// wf2: VW only (needs G). W_VW[n][k] = sum_c famv[k][c]*G[c][n].
__global__ void __launch_bounds__(256) wf2(const float* fv, const float* G, bhalf* FW) {
  int k = blockIdx.x, tid = threadIdx.x;
  float a = 0.f;
  for (int c = 0; c < 256; ++c)
    a = fmaf(fv[(size_t)k*256 + c], G[(size_t)c*256 + tid], a);
  FW[FW_VW + (size_t)tid*256 + k] = f2b(a);
}

// ---------- MFMA chain: everything from PT, B-operand STAGED IN LDS ----------
__global__ void __launch_bounds__(256, 4) kv1(const bhalf* PT, const bhalf* WT, const bhalf* FW,
                                              bhalf* K1B, bhalf* VQT, bhalf* VKT, bhalf* VWT,
                                              bhalf* Q2B) {
  __shared__ bhalf Wl[64*256];   // 32 KB, swizzled rows of 512 B
  int bt = blockIdx.x, part = blockIdx.y;
  int tid = threadIdx.x, w = tid >> 6, l = tid & 63;
  // resolve weight tile (64 rows from row nt0*16) and A source
  const bhalf* Wsrc; int nt0;
  const bhalf* A;
  if (part >= 10) {
    int u = (part - 10) >> 1;
    nt0 = ((part - 10) & 1) * 4;
    Wsrc = WT + W_FAMQ;
    A = PT + (size_t)(bt*5 + u)*16384;
  } else if (part < 2) {
    nt0 = part*4; Wsrc = WT + W_FAMK; A = PT + (size_t)bt*5*16384;
  } else if (part < 6) {
    nt0 = ((part - 2) & 1) * 4;
    Wsrc = FW + (((part - 2) >> 1) == 0 ? FW_VQ : FW_VK);
    A = PT + (size_t)bt*5*16384;
  } else {
    nt0 = (part - 6)*4; Wsrc = FW + FW_VW; A = PT + (size_t)bt*5*16384;
  }
  // A fragments (8 independent global loads, overlap with staging)
  bf8v a8[8];
  #pragma unroll
  for (int kt = 0; kt < 8; ++kt) a8[kt] = ldfrag(A, w*16, kt*32, 256, l);
  // stage weight tile: rows [nt0*16, nt0*16+64) x 256 cols, swizzled 512 B rows
  {
    const char* gw = reinterpret_cast<const char*>(Wsrc + (size_t)nt0*16*256);
    char* lw = reinterpret_cast<char*>(Wl);
    #pragma unroll
    for (int c = 0; c < 8; ++c) {
      int x = (c*256 + tid) << 4;                 // row = x>>9 (512 B rows)
      float4 val = *reinterpret_cast<const float4*>(gw + x);
      *reinterpret_cast<float4*>(lw + (x ^ (((x >> 9) & 7) << 4))) = val;
    }
  }
  __syncthreads();
  // compute 4 nt columns from LDS
  __builtin_amdgcn_s_setprio(1);
  f4 accs[4];
  #pragma unroll
  for (int nn = 0; nn < 4; ++nn) {
    f4 acc = {0.f,0.f,0.f,0.f};
    #pragma unroll
    for (int kt = 0; kt < 8; ++kt)
      acc = mfma16(a8[kt], ldswz(Wl, nn*16 + (l & 15), kt*64 + ((l >> 4) << 4), 512), acc);
    accs[nn] = acc;
  }
  __builtin_amdgcn_s_setprio(0);
  // stores per part type
  if (part >= 10) {
    int u = (part - 10) >> 1;
    bhalf* q1 = Q2B + (size_t)(bt*5 + u)*8192;
    #pragma unroll
    for (int nn = 0; nn < 4; ++nn) {
      int nt = nt0 + nn;
      #pragma unroll
      for (int reg = 0; reg < 4; ++reg) {
        int p = w*16 + ((l>>4)<<2) + reg;
        q1[(size_t)p*128 + nt*16 + (l&15)] = f2b(accs[nn][reg]);
      }
    }
  } else if (part < 2) {
    bhalf* dst = K1B + (size_t)bt*8192;
    #pragma unroll
    for (int nn = 0; nn < 4; ++nn) {
      int nt = nt0 + nn;
      #pragma unroll
      for (int reg = 0; reg < 4; ++reg) {
        int p = w*16 + ((l>>4)<<2) + reg;
        dst[(size_t)p*128 + nt*16 + (l&15)] = f2b(accs[nn][reg]);
      }
    }
  } else if (part < 6) {
    bhalf* o = ((((part - 2) >> 1) == 0) ? VQT : VKT) + (size_t)bt*8192;
    #pragma unroll
    for (int nn = 0; nn < 4; ++nn) {
      int n = (nt0 + nn)*16 + (l&15);
      int p0 = w*16 + ((l>>4)<<2);
      us4 pk = { f2b(accs[nn][0]), f2b(accs[nn][1]), f2b(accs[nn][2]), f2b(accs[nn][3]) };
      *reinterpret_cast<us4*>(o + (size_t)n*64 + p0) = pk;
    }
  } else {
    bhalf* ow = VWT + (size_t)bt*16384;
    #pragma unroll
    for (int nn = 0; nn < 4; ++nn) {
      int n = (nt0 + nn)*16 + (l&15);
      int p0 = w*16 + ((l>>4)<<2);
      us4 pk = { f2b(accs[nn][0]), f2b(accs[nn][1]), f2b(accs[nn][2]), f2b(accs[nn][3]) };
      *reinterpret_cast<us4*>(ow + (size_t)n*64 + p0) = pk;
    }
  }
}

// ---------- stage 1: FAM attention + ARM input projections (phase-1-free) ----------
__global__ void __launch_bounds__(256) s1ker(const bhalf* WT,
    const bhalf* K1B, const bhalf* VQT, const bhalf* VKT, const bhalf* VWT,
    bhalf* Q2B, bhalf* K2B, bhalf* W2T)
{
  __shared__ bhalf bufP[64*72];   // 9.2 KB, cross-wave P
  int orig = blockIdx.x;
  int blk = (orig & 7) * 80 + (orig >> 3);   // bijective XCD grouping
  int bt = blk / 5;
  int tid = threadIdx.x, w = tid >> 6, l = tid & 63;
  // phase 2: scores vs k1 (q1 fragments from Q2B), softmax in regs
  float sv[4][4];
  {
    const bhalf* Q1 = Q2B + (size_t)blk*8192;
    const bhalf* K1 = K1B + (size_t)bt*8192;
    bf8v aq[4];
    #pragma unroll
    for (int kt = 0; kt < 4; ++kt) aq[kt] = ldfrag(Q1, w*16, kt*32, 128, l);
    __builtin_amdgcn_s_setprio(1);
    #pragma unroll
    for (int nt = 0; nt < 4; ++nt) {
      f4 acc = {0.f,0.f,0.f,0.f};
      #pragma unroll
      for (int kt = 0; kt < 4; ++kt)
        acc = mfma16(aq[kt], ldfrag(K1, nt*16, kt*32, 128, l), acc);
      #pragma unroll
      for (int reg = 0; reg < 4; ++reg) sv[nt][reg] = acc[reg] * ATT_SCALE;
    }
    __builtin_amdgcn_s_setprio(0);
  }
  if ((l & 15) > 0) { sv[3][0] = -1e30f; sv[3][1] = -1e30f; sv[3][2] = -1e30f; sv[3][3] = -1e30f; }
  regSoftmax(sv);
  #pragma unroll
  for (int nt = 0; nt < 4; ++nt)
    #pragma unroll
    for (int reg = 0; reg < 4; ++reg)
      bufP[(w*16 + ((l>>4)<<2) + reg)*72 + nt*16 + (l&15)] = f2b(sv[nt][reg]);
  __syncthreads();   // bufP cross-wave
  // phase 3: column-split PVs. A-frags: all 4 row-groups of P.
  bf8v ap0[4], ap1[4];
  #pragma unroll
  for (int g = 0; g < 4; ++g) {
    ap0[g] = ldfrag(bufP, g*16, 0, 72, l);
    ap1[g] = ldfrag(bufP, g*16, 32, 72, l);
  }
  const bhalf* vq = VQT + (size_t)bt*8192;
  const bhalf* vk = VKT + (size_t)bt*8192;
  const bhalf* vw = VWT + (size_t)bt*16384;
  bhalf* q2 = Q2B + (size_t)blk*8192;
  bhalf* k2 = K2B + (size_t)blk*8192;
  bhalf* w2 = W2T + (size_t)blk*16384;
  __builtin_amdgcn_s_setprio(1);
  #pragma unroll
  for (int nn = 0; nn < 2; ++nn) {     // q2 cols nt = 2w+nn (overwrites q1 slot)
    int nt = w*2 + nn;
    bf8v b0 = ldfrag(vq, nt*16, 0, 64, l);
    bf8v b1 = ldfrag(vq, nt*16, 32, 64, l);
    f4 acc[4];
    #pragma unroll
    for (int g = 0; g < 4; ++g) {
      f4 z = {0.f,0.f,0.f,0.f};
      z = mfma16(ap0[g], b0, z);
      acc[g] = mfma16(ap1[g], b1, z);
    }
    int c = nt*16 + (l & 15);
    #pragma unroll
    for (int g = 0; g < 4; ++g)
      #pragma unroll
      for (int reg = 0; reg < 4; ++reg) {
        int p = g*16 + ((l>>4)<<2) + reg;
        q2[(size_t)p*128 + c] = (p < 49) ? f2b(acc[g][reg]) : (bhalf)0;
      }
  }
  #pragma unroll
  for (int nn = 0; nn < 2; ++nn) {     // k2 cols nt = 2w+nn
    int nt = w*2 + nn;
    bf8v b0 = ldfrag(vk, nt*16, 0, 64, l);
    bf8v b1 = ldfrag(vk, nt*16, 32, 64, l);
    f4 acc[4];
    #pragma unroll
    for (int g = 0; g < 4; ++g) {
      f4 z = {0.f,0.f,0.f,0.f};
      z = mfma16(ap0[g], b0, z);
      acc[g] = mfma16(ap1[g], b1, z);
    }
    int c = nt*16 + (l & 15);
    #pragma unroll
    for (int g = 0; g < 4; ++g)
      #pragma unroll
      for (int reg = 0; reg < 4; ++reg) {
        int p = g*16 + ((l>>4)<<2) + reg;
        k2[(size_t)p*128 + c] = (p < 49) ? f2b(acc[g][reg]) : (bhalf)0;
      }
  }
  #pragma unroll
  for (int nn = 0; nn < 4; ++nn) {     // w2t cols nt = 4w+nn, PACKED transposed store
    int nt = w*4 + nn;
    bf8v b0 = ldfrag(vw, nt*16, 0, 64, l);
    bf8v b1 = ldfrag(vw, nt*16, 32, 64, l);
    f4 acc[4];
    #pragma unroll
    for (int g = 0; g < 4; ++g) {
      f4 z = {0.f,0.f,0.f,0.f};
      z = mfma16(ap0[g], b0, z);
      acc[g] = mfma16(ap1[g], b1, z);
    }
    int c = nt*16 + (l & 15);
    int p0 = (l >> 4) << 2;
    #pragma unroll
    for (int g = 0; g < 4; ++g) {
      int pb = g*16 + p0;
      us4 pk = { (bhalf)((pb+0 < 49) ? f2b(acc[g][0]) : 0),
                 (bhalf)((pb+1 < 49) ? f2b(acc[g][1]) : 0),
                 (bhalf)((pb+2 < 49) ? f2b(acc[g][2]) : 0),
                 (bhalf)((pb+3 < 49) ? f2b(acc[g][3]) : 0) };
      *reinterpret_cast<us4*>(w2 + (size_t)c*64 + pb) = pk;
    }
  }
  __builtin_amdgcn_s_setprio(0);
}

// ---------- stage 2: ARM attention + edge stats (column-split PV, V in registers) ----------
__global__ void __launch_bounds__(256) s2ker(const bhalf* Q2B, const bhalf* K2B, const bhalf* W2T,
    const float* epb, float* hws, bhalf* hwsb, float* gs1, float* gs2)
{
  __shared__ bhalf Kl[64*128];    // 16 KB, swizzled rows of 256 B
  __shared__ bhalf bufP[64*72];   // 9 KB, full P (cross-wave)
  __shared__ float redH[256];     // 1 KB, per-wave disjoint columns
  __shared__ float redS[8];
  int orig = blockIdx.x;
  int blk = (orig & 7) * 400 + (orig >> 3);   // 3200 = 8*400, bijective XCD grouping
  int e = blk % 25, bt = blk / 25, b = bt >> 4, t = bt & 15;
  int i = e / 5, j = e % 5;
  int tid = threadIdx.x, w = tid >> 6, l = tid & 63;
  const bhalf* K = K2B + (size_t)(bt*5 + i)*8192;
  const bhalf* V = W2T + (size_t)(bt*5 + i)*16384;
  const bhalf* Q = Q2B + (size_t)(bt*5 + j)*8192;
  // prefetch Q fragments (independent of LDS staging)
  bf8v aq[4];
  #pragma unroll
  for (int kt = 0; kt < 4; ++kt) aq[kt] = ldfrag(Q, w*16, kt*32, 128, l);
  // ---- stage K (16 KB): coalesced global read, swizzled LDS write ----
  {
    const char* gk = reinterpret_cast<const char*>(K);
    char* lk = reinterpret_cast<char*>(Kl);
    #pragma unroll
    for (int c = 0; c < 4; ++c) {
      int x = (c*256 + tid) << 4;                 // K: row = x>>8 (256 B rows)
      float4 val = *reinterpret_cast<const float4*>(gk + x);
      *reinterpret_cast<float4*>(lk + (x ^ (((x >> 8) & 7) << 4))) = val;
    }
  }
  __syncthreads();
  // QK^T from LDS + in-register softmax
  float sv[4][4];
  __builtin_amdgcn_s_setprio(1);
  #pragma unroll
  for (int nt = 0; nt < 4; ++nt) {
    f4 acc = {0.f,0.f,0.f,0.f};
    #pragma unroll
    for (int kt = 0; kt < 4; ++kt)
      acc = mfma16(aq[kt], ldswz(Kl, nt*16 + (l & 15), kt*64 + ((l >> 4) << 4), 256), acc);
    #pragma unroll
    for (int reg = 0; reg < 4; ++reg) sv[nt][reg] = acc[reg] * ATT_SCALE;
  }
  __builtin_amdgcn_s_setprio(0);
  if ((l & 15) > 0) { sv[3][0] = -1e30f; sv[3][1] = -1e30f; sv[3][2] = -1e30f; sv[3][3] = -1e30f; }
  regSoftmax(sv);
  // write own P rows to bufP
  #pragma unroll
  for (int nt = 0; nt < 4; ++nt)
    #pragma unroll
    for (int reg = 0; reg < 4; ++reg)
      bufP[(w*16 + ((l>>4)<<2) + reg)*72 + nt*16 + (l&15)] = f2b(sv[nt][reg]);
  // V fragments for this wave's column slice (rows [w*64, w*64+64) of W2T tile)
  bf8v vf0[4], vf1[4];
  #pragma unroll
  for (int nn = 0; nn < 4; ++nn) {
    vf0[nn] = ldfrag(V, (w*4 + nn)*16, 0, 64, l);
    vf1[nn] = ldfrag(V, (w*4 + nn)*16, 32, 64, l);
  }
  __syncthreads();   // bufP complete (cross-wave read next)
  // A-fragments: all 4 row-groups of P
  bf8v ap0[4], ap1[4];
  #pragma unroll
  for (int g = 0; g < 4; ++g) {
    ap0[g] = ldfrag(bufP, g*16, 0, 72, l);
    ap1[g] = ldfrag(bufP, g*16, 32, 72, l);
  }
  float sqa = 0.f;
  __builtin_amdgcn_s_setprio(1);
  #pragma unroll
  for (int nn = 0; nn < 4; ++nn) {
    f4 acc[4];
    #pragma unroll
    for (int g = 0; g < 4; ++g) {
      f4 z = {0.f,0.f,0.f,0.f};
      z = mfma16(ap0[g], vf0[nn], z);
      acc[g] = mfma16(ap1[g], vf1[nn], z);
    }
    int c = ((w*4 + nn) << 4) + (l & 15);
    float bias = epb[c];
    float hw = 0.f;
    #pragma unroll
    for (int g = 0; g < 4; ++g) {
      #pragma unroll
      for (int reg = 0; reg < 4; ++reg) {
        int p = g*16 + ((l>>4)<<2) + reg;
        if (p < 49) { float v = acc[g][reg] + bias; hw += v; sqa += v*v; }
      }
    }
    hw += __shfl_xor(hw, 16);
    hw += __shfl_xor(hw, 32);
    if ((l >> 4) == 0) redH[c] = hw;   // per-wave disjoint c
  }
  __builtin_amdgcn_s_setprio(0);
  __syncthreads();
  float hwtot = redH[tid];
  size_t oidx = (((size_t)(b*25+e)*16) + t)*256 + tid;
  hws[oidx] = hwtot;
  hwsb[oidx] = f2b(hwtot);
  int slot = (orig & 7)*32 + e;
  reduce2Atomic(hwtot, sqa, gs1 + slot, gs2 + slot, redS);
}

// ---------- GNN back-half (verified fusions, per-XCD stat shards) ----------

// node MFMA projections, L0: 160 blocks (m in {A,B,U,V}, 10 row-tiles x 4 col-tiles).
__global__ void __launch_bounds__(256, 2) gnnProjN(const bhalf* Xb, const bhalf* GW,
    float* xA, float* xB, float* xU, float* xV) {
  __shared__ bhalf Wl[64*256];   // 32 KB
  int blk = blockIdx.x;
  int tid = threadIdx.x, w = tid >> 6, l = tid & 63;
  int m = blk / 40, rem = blk % 40, rt = rem >> 2, ct = rem & 3;
  const bhalf* A = Xb + (size_t)rt*64*256;
  const bhalf* Wsrc = GW + (size_t)m*65536;
  float* dst = (m==0)?xA:(m==1)?xB:(m==2)?xU:xV;
  bf8v a8[8];
  #pragma unroll
  for (int kt = 0; kt < 8; ++kt) a8[kt] = ldfrag(A, w*16, kt*32, 256, l);
  {
    const char* gw = reinterpret_cast<const char*>(Wsrc + (size_t)ct*64*256);
    char* lw = reinterpret_cast<char*>(Wl);
    #pragma unroll
    for (int c = 0; c < 8; ++c) {
      int x = (c*256 + tid) << 4;
      float4 val = *reinterpret_cast<const float4*>(gw + x);
      *reinterpret_cast<float4*>(lw + (x ^ (((x >> 9) & 7) << 4))) = val;
    }
  }
  __syncthreads();
  __builtin_amdgcn_s_setprio(1);
  f4 accs[4];
  #pragma unroll
  for (int nn = 0; nn < 4; ++nn) {
    f4 acc = {0.f,0.f,0.f,0.f};
    #pragma unroll
    for (int kt = 0; kt < 8; ++kt)
      acc = mfma16(a8[kt], ldswz(Wl, nn*16 + (l & 15), kt*64 + ((l >> 4) << 4), 512), acc);
    accs[nn] = acc;
  }
  __builtin_amdgcn_s_setprio(0);
  int p0 = w*16 + ((l>>4)<<2);
  size_t rbase = (size_t)rt*64 + p0;
  #pragma unroll
  for (int nn = 0; nn < 4; ++nn) {
    int n = ct*64 + nn*16 + (l&15);
    #pragma unroll
    for (int reg = 0; reg < 4; ++reg)
      dst[(rbase + reg)*256 + n] = accs[nn][reg];
  }
}

// node MFMA projections, L1 variant: A computed ON THE FLY as
// FVnew = relu(FVold + bn0(XN0)) (g3b fused into the A-fragment prologue;
// compile-time specialization -- no runtime branch in any loop; r20 lesson).
// BN params wave-uniform: i = (rt*4 + w) % 5.
__global__ void __launch_bounds__(256, 2) gnnProjNL1(const float* FVold, const float* XN0,
    const bhalf* GW, const float* g0, const float* b0, const float* ns1, const float* ns2,
    float* xA, float* xB, float* xU, float* xV) {
  __shared__ bhalf Wl[64*256];   // 32 KB
  int blk = blockIdx.x;
  int tid = threadIdx.x, w = tid >> 6, l = tid & 63;
  int m = blk / 40, rem = blk % 40, rt = rem >> 2, ct = rem & 3;
  const bhalf* Wsrc = GW + (size_t)m*65536;
  float* dst = (m==0)?xA:(m==1)?xB:(m==2)?xU:xV;
  // bn0 params (wave-uniform node index)
  int i = (rt*4 + w) % 5;
  constexpr float inv32k = 1.f/32768.f;
  float m0 = sumShards(ns1, i)*inv32k;
  float var0 = sumShards(ns2, i)*inv32k - m0*m0;
  float r0 = rsqrtf(var0 + 1e-5f);
  float gi = g0[i], bi = b0[i];
  int row = rt*64 + w*16 + (l & 15);
  // A fragments: FVnew computed on the fly (matches g3b's f32 math + f2b exactly)
  bf8v a8[8];
  #pragma unroll
  for (int kt = 0; kt < 8; ++kt) {
    size_t base = (size_t)row*256 + kt*32 + ((l >> 4) << 3);
    float4 fa = *reinterpret_cast<const float4*>(&FVold[base]);
    float4 fb = *reinterpret_cast<const float4*>(&FVold[base + 4]);
    float4 xa = *reinterpret_cast<const float4*>(&XN0[base]);
    float4 xb = *reinterpret_cast<const float4*>(&XN0[base + 4]);
    float xv[8] = {xa.x, xa.y, xa.z, xa.w, xb.x, xb.y, xb.z, xb.w};
    float fv[8] = {fa.x, fa.y, fa.z, fa.w, fb.x, fb.y, fb.z, fb.w};
    #pragma unroll
    for (int q = 0; q < 8; ++q) {
      float v = gi*((xv[q] - m0)*r0) + bi;
      if (v != v) v = 0.f;               // L0 NaN mask
      a8[kt][q] = (short)f2b(fmaxf(fv[q] + v, 0.f));
    }
  }
  {
    const char* gw = reinterpret_cast<const char*>(Wsrc + (size_t)ct*64*256);
    char* lw = reinterpret_cast<char*>(Wl);
    #pragma unroll
    for (int c = 0; c < 8; ++c) {
      int x = (c*256 + tid) << 4;
      float4 val = *reinterpret_cast<const float4*>(gw + x);
      *reinterpret_cast<float4*>(lw + (x ^ (((x >> 9) & 7) << 4))) = val;
    }
  }
  __syncthreads();
  __builtin_amdgcn_s_setprio(1);
  f4 accs[4];
  #pragma unroll
  for (int nn = 0; nn < 4; ++nn) {
    f4 acc = {0.f,0.f,0.f,0.f};
    #pragma unroll
    for (int kt = 0; kt < 8; ++kt)
      acc = mfma16(a8[kt], ldswz(Wl, nn*16 + (l & 15), kt*64 + ((l >> 4) << 4), 512), acc);
    accs[nn] = acc;
  }
  __builtin_amdgcn_s_setprio(0);
  int p0 = w*16 + ((l>>4)<<2);
  size_t rbase = (size_t)rt*64 + p0;
  #pragma unroll
  for (int nn = 0; nn < 4; ++nn) {
    int n = ct*64 + nn*16 + (l&15);
    #pragma unroll
    for (int reg = 0; reg < 4; ++reg)
      dst[(rbase + reg)*256 + n] = accs[nn][reg];
  }
}

// edge MFMA projection FUSED with g2a: 200 blocks (50 row-tiles x 4 col-tiles).
__global__ void __launch_bounds__(256, 2) gnnProjE(const bhalf* Eb, const bhalf* GW,
    const float* CSE, const float* gs1, const float* gs2, const float* gg, const float* gb,
    int bnfly, const float* xA, const float* xB, float* ET, float* es1, float* es2) {
  __shared__ bhalf Wl[64*256];   // 32 KB
  int blk = blockIdx.x;
  int tid = threadIdx.x, w = tid >> 6, l = tid & 63;
  int rt = blk >> 2, ct = blk & 3;
  const bhalf* A = Eb + (size_t)rt*64*256;
  bf8v a8[8];
  #pragma unroll
  for (int kt = 0; kt < 8; ++kt) a8[kt] = ldfrag(A, w*16, kt*32, 256, l);
  {
    const char* gw = reinterpret_cast<const char*>(GW + (size_t)ct*64*256);
    char* lw = reinterpret_cast<char*>(Wl);
    #pragma unroll
    for (int c = 0; c < 8; ++c) {
      int x = (c*256 + tid) << 4;
      float4 val = *reinterpret_cast<const float4*>(gw + x);
      *reinterpret_cast<float4*>(lw + (x ^ (((x >> 9) & 7) << 4))) = val;
    }
  }
  __syncthreads();
  __builtin_amdgcn_s_setprio(1);
  f4 accs[4];
  #pragma unroll
  for (int nn = 0; nn < 4; ++nn) {
    f4 acc = {0.f,0.f,0.f,0.f};
    #pragma unroll
    for (int kt = 0; kt < 8; ++kt)
      acc = mfma16(a8[kt], ldswz(Wl, nn*16 + (l & 15), kt*64 + ((l >> 4) << 4), 512), acc);
    accs[nn] = acc;
  }
  __builtin_amdgcn_s_setprio(0);
  // epilogue (uniform per wave; no branches inside the store loops)
  int be = rt*4 + w;              // (b*25+e)
  int b = be / 25, e = be % 25;
  int i = e / 5, j = e % 5;
  const float* xAr = xA + ((size_t)(b*5+i)*16)*256;
  const float* xBr = xB + ((size_t)(b*5+j)*16)*256;
  float scl = 1.f, ofs = 0.f;
  if (bnfly) {
    constexpr float invCnt = 1.f/1605632.f;
    float m = sumShards(gs1, e)*invCnt;
    float var = sumShards(gs2, e)*invCnt - m*m;
    float rstd = rsqrtf(var + 1e-5f);
    float g = gg[e]*rstd;
    scl = g * (1.f/49.f);
    ofs = gb[e] - g*m;
  }
  int t0 = (l>>4)<<2;
  float s1l = 0.f, s2l = 0.f;
  #pragma unroll
  for (int nn = 0; nn < 4; ++nn) {
    int n = ct*64 + nn*16 + (l&15);
    float cs = CSE[n] * ofs;      // ofs==0 for L1 -> cs==0
    #pragma unroll
    for (int reg = 0; reg < 4; ++reg) {
      int t = t0 + reg;
      float ve = fmaf(accs[nn][reg], scl, cs);
      float vfull = xAr[(size_t)t*256 + n] + xBr[(size_t)t*256 + n] + ve;
      ET[((size_t)be*16 + t)*256 + n] = vfull;
      s1l += vfull; s2l += vfull*vfull;
    }
  }
  #pragma unroll
  for (int off = 32; off; off >>= 1) { s1l += __shfl_down(s1l, off); s2l += __shfl_down(s2l, off); }
  if (l == 0) {
    int slot = (blk & 7)*32 + e;
    atomicAdd(es1 + slot, s1l);
    atomicAdd(es2 + slot, s2l);
  }
}

// fused g2b+g3a. Stats read as 8-shard sums; ns written to per-XCD shard.
// L0 additionally writes the bf16 copy of EDG (for the L1 MFMA projection).
__global__ void __launch_bounds__(256) g2bg3a(const float* ET, const float* HWS, const float* EDGin,
    float* EDGout, bhalf* EDGb, const float* xV, const float* xU, float* XN,
    const float* gs1, const float* gs2, const float* gemg, const float* gemb,
    const float* bg, const float* bb2, const float* es1, const float* es2,
    float* ns1, float* ns2, const float* efw, const float* efb, float* out, int layer) {
  __shared__ float red[8];
  int blk = blockIdx.x, tid = threadIdx.x;
  int b = blk / 80, i = (blk >> 4) % 5, t = blk & 15;
  constexpr float inv32k = 1.f/32768.f;
  constexpr float invCnt = 1.f/1605632.f;
  float ssum = 0.f, exv[5], xvv[5];
  #pragma unroll
  for (int j = 0; j < 5; ++j) {
    int e = i*5 + j;
    size_t ee = ((size_t)(b*25 + e)*16 + t)*256 + tid;
    float m = sumShards(es1, e)*inv32k;
    float var = sumShards(es2, e)*inv32k - m*m;
    float rstd = rsqrtf(var + 1e-5f);
    float v = bg[e]*((ET[ee]-m)*rstd) + bb2[e];
    if (v != v) v = 0.f;
    float base;
    if (layer == 0) {
      float gm = sumShards(gs1, e)*invCnt;
      float gvar = sumShards(gs2, e)*invCnt - gm*gm;
      float gr = rsqrtf(gvar + 1e-5f);
      base = gemg[e]*((HWS[ee]*(1.f/49.f) - gm)*gr) + gemb[e];
    } else {
      base = EDGin[ee];
    }
    float edg = base + fmaxf(v, 0.f);
    if (layer == 0) {
      EDGout[ee] = edg;
      EDGb[ee] = f2b(edg);
    } else {
      // fused finker edge part
      float vv = edg * efw[tid];
      #pragma unroll
      for (int off = 32; off; off >>= 1) vv += __shfl_down(vv, off);
      if ((tid & 63) == 0) red[tid >> 6] = vv;
      __syncthreads();
      if (tid == 0) out[640 + (size_t)(b*25 + e)*16 + t] = red[0]+red[1]+red[2]+red[3] + efb[0];
      __syncthreads();
    }
    float sg = 1.f/(1.f + __expf(-edg));
    exv[j] = __expf(sg);
    ssum += exv[j];
    xvv[j] = xV[((size_t)(b*5+j)*16 + t)*256 + tid];
  }
  float agg = 0.f;
  #pragma unroll
  for (int j = 0; j < 5; ++j) agg += exv[j]*xvv[j];
  agg *= 0.2f/ssum;
  float xn = xU[(size_t)blk*256 + tid] + agg;
  XN[(size_t)blk*256 + tid] = xn;
  int slot = (blk & 7)*32 + i;
  reduce2Atomic(xn, xn*xn, ns1 + slot, ns2 + slot, red);
}

// L1 node BN + residual relu fused with finker node part. FVnew (the g3b-L0
// result) is recomputed on the fly from FVold + bn0(XN0) -- r20-verified math.
__global__ void __launch_bounds__(256) g3bfin(const float* XN1, const float* XN0, const float* FVold,
    const float* g1v, const float* b1v, const float* s1_1, const float* s2_1,
    const float* g0v, const float* b0v, const float* s1_0, const float* s2_0,
    const float* sc, float* out) {
  __shared__ float red[12];
  int blk = blockIdx.x, tid = threadIdx.x;
  int i = (blk >> 4) % 5;
  size_t ni = (size_t)blk*256 + tid;
  constexpr float inv32k = 1.f/32768.f;
  // reconstruct FVnew = relu(FVold + bn0(XN0)) with L0 NaN mask
  float m0 = sumShards(s1_0, i)*inv32k;
  float var0 = sumShards(s2_0, i)*inv32k - m0*m0;
  float rstd0 = rsqrtf(var0 + 1e-5f);
  float v0 = g0v[i]*((XN0[ni]-m0)*rstd0) + b0v[i];
  if (v0 != v0) v0 = 0.f;
  float fvnew = fmaxf(FVold[ni] + v0, 0.f);
  // L1 BN (no NaN mask) + residual relu
  float m1 = sumShards(s1_1, i)*inv32k;
  float var1 = sumShards(s2_1, i)*inv32k - m1*m1;
  float rstd1 = rsqrtf(var1 + 1e-5f);
  float v1 = g1v[i]*((XN1[ni]-m1)*rstd1) + b1v[i];
  float x = fmaxf(fvnew + v1, 0.f);
  float s = fmaxf(sc[i*256 + tid], 0.f);
  float xx = x*x, ss = s*s, xs = x*s;
  #pragma unroll
  for (int off = 32; off; off >>= 1) {
    xx += __shfl_down(xx, off); ss += __shfl_down(ss, off); xs += __shfl_down(xs, off);
  }
  if ((tid & 63) == 0) { int w = tid >> 6; red[w*3] = xx; red[w*3+1] = ss; red[w*3+2] = xs; }
  __syncthreads();
  if (tid == 0) {
    float sxx = red[0]+red[3]+red[6]+red[9];
    float sss = red[1]+red[4]+red[7]+red[10];
    float sxs = red[2]+red[5]+red[8]+red[11];
    float nx = fmaxf(sqrtf(sxx), 1e-12f);
    float ns = fmaxf(sqrtf(sss), 1e-12f);
    out[blk] = sxs / (nx * ns);
  }
}

// ---------- host ----------

extern "C" void kernel_launch(void* const* d_in, const int* in_sizes, int n_in,
                              void* d_out, int out_size, void* d_ws, size_t ws_size,
                              hipStream_t stream) {
  (void)in_sizes; (void)n_in; (void)out_size; (void)ws_size;
  const float* af    = (const float*)d_in[0];
  const float* ef    = (const float*)d_in[1];
  const float* gfm   = (const float*)d_in[2];
  const float* attf  = (const float*)d_in[3];
  const float* sfm   = (const float*)d_in[4];
  const float* fam_q = (const float*)d_in[5];
  const float* fam_k = (const float*)d_in[6];
  const float* fam_v = (const float*)d_in[7];
  const float* arm_q = (const float*)d_in[8];
  const float* arm_k = (const float*)d_in[9];
  const float* arm_v = (const float*)d_in[10];
  const float* epw   = (const float*)d_in[11];
  const float* epb   = (const float*)d_in[12];
  const float* gemg  = (const float*)d_in[13];
  const float* gemb  = (const float*)d_in[14];
  const float* Us[2]   = {(const float*)d_in[15], (const float*)d_in[20]};
  const float* Vs[2]   = {(const float*)d_in[16], (const float*)d_in[21]};
  const float* As[2]   = {(const float*)d_in[17], (const float*)d_in[22]};
  const float* Bs[2]   = {(const float*)d_in[18], (const float*)d_in[23]};
  const float* Es[2]   = {(const float*)d_in[19], (const float*)d_in[24]};
  const float* bnvg[2] = {(const float*)d_in[25], (const float*)d_in[29]};
  const float* bnvb[2] = {(const float*)d_in[26], (const float*)d_in[30]};
  const float* bneg[2] = {(const float*)d_in[27], (const float*)d_in[31]};
  const float* bneb[2] = {(const float*)d_in[28], (const float*)d_in[32]};
  const float* scp  = (const float*)d_in[33];
  const float* efw  = (const float*)d_in[34];
  const float* efb  = (const float*)d_in[35];

  char* ws = (char*)d_ws;
  bhalf* PT  = (bhalf*)(ws + O_PT);
  bhalf* WTS = (bhalf*)(ws + O_WTS);
  bhalf* K1B = (bhalf*)(ws + O_K1B);
  bhalf* FW  = (bhalf*)(ws + O_FW);
  bhalf* VQT = (bhalf*)(ws + O_VQT);
  bhalf* VKT = (bhalf*)(ws + O_VKT);
  float* G   = (float*)(ws + O_G);
  bhalf* VWT = (bhalf*)(ws + O_VWT);
  bhalf* Q2B = (bhalf*)(ws + O_Q2B);
  bhalf* K2B = (bhalf*)(ws + O_K2B);
  bhalf* W2T = (bhalf*)(ws + O_W2T);
  float* FV  = (float*)(ws + O_FV);
  float* HWS = (float*)(ws + O_HWS);
  float* EDG = (float*)(ws + O_EDG);
  float* XA  = (float*)(ws + O_XA);
  float* XB  = (float*)(ws + O_XB);
  float* XU  = (float*)(ws + O_XU);
  float* XV  = (float*)(ws + O_XV);
  float* ET  = (float*)(ws + O_ET);
  float* XN0 = (float*)(ws + O_XN);
  float* XN1 = (float*)(ws + O_EE);   // reuses the old eE region
  bhalf* GWT = (bhalf*)(ws + O_GWT);
  float* CSE = (float*)(ws + O_CSE);
  bhalf* FVB = (bhalf*)(ws + O_FVB);
  bhalf* HWB = (bhalf*)(ws + O_HWB);
  bhalf* EDB = (bhalf*)(ws + O_EDB);
  float* ST2 = (float*)(ws + O_ST2);  // fresh region; zeroed by prepAll

  prepAll<<<4993, TPB, 0, stream>>>(fam_q, fam_k, fam_v, arm_q, arm_k, arm_v, epw, WTS,
                                    af, ef, gfm, attf, sfm, PT, FV, G,
                                    As[0], Bs[0], Us[0], Vs[0], Es[0],
                                    As[1], Bs[1], Us[1], Vs[1], Es[1],
                                    GWT, CSE, FVB, FW, ST2);
  wf2<<<256, TPB, 0, stream>>>(fam_v, G, FW);
  // kv1 grid 128x20: parts 0-9 as before, parts 10-19 compute q1 -> Q2B
  kv1<<<dim3(128, 20), TPB, 0, stream>>>(PT, WTS, FW, K1B, VQT, VKT, VWT, Q2B);
  s1ker<<<640, TPB, 0, stream>>>(WTS, K1B, VQT, VKT, VWT, Q2B, K2B, W2T);
  s2ker<<<3200, TPB, 0, stream>>>(Q2B, K2B, W2T, epb, HWS, HWB, ST2 + ST_GS1, ST2 + ST_GS2);

  float* out = (float*)d_out;
  float* es1_0 = ST2 + 512;          float* es2_0 = ST2 + 768;
  float* ns1_0 = ST2 + 1024;         float* ns2_0 = ST2 + 1280;
  float* es1_1 = ST2 + 512 + 1024;   float* es2_1 = ST2 + 768 + 1024;
  float* ns1_1 = ST2 + 1024 + 1024;  float* ns2_1 = ST2 + 1280 + 1024;

  for (int L = 0; L < 2; ++L) {
    float* es1 = (L == 0) ? es1_0 : es1_1;
    float* es2 = (L == 0) ? es2_0 : es2_1;
    float* ns1 = (L == 0) ? ns1_0 : ns1_1;
    float* ns2 = (L == 0) ? ns2_0 : ns2_1;
    if (L == 0)
      gnnProjN<<<160, TPB, 0, stream>>>(FVB, GWT, XA, XB, XU, XV);
    else
      gnnProjNL1<<<160, TPB, 0, stream>>>(FV, XN0, GWT + (size_t)5*65536,
                                          bnvg[0], bnvb[0], ns1_0, ns2_0,
                                          XA, XB, XU, XV);
    gnnProjE<<<200, TPB, 0, stream>>>((L == 0) ? HWB : EDB,
                                      GWT + (size_t)L*5*65536 + (size_t)4*65536, CSE,
                                      ST2 + ST_GS1, ST2 + ST_GS2, gemg, gemb, (L == 0) ? 1 : 0,
                                      XA, XB, ET, es1, es2);
    g2bg3a<<<640, TPB, 0, stream>>>(ET, HWS, EDG, EDG, EDB, XV, XU, (L == 0) ? XN0 : XN1,
                                    ST2 + ST_GS1, ST2 + ST_GS2, gemg, gemb,
                                    bneg[L], bneb[L], es1, es2, ns1, ns2,
                                    efw, efb, out, L);
  }
  g3bfin<<<640, TPB, 0, stream>>>(XN1, XN0, FV,
                                  bnvg[1], bnvb[1], ns1_1, ns2_1,
                                  bnvg[0], bnvb[0], ns1_0, ns2_0,
                                  scp, out);
}

// Round 26
// 165.438 us; speedup vs baseline: 1.0164x; 1.0164x over previous
//
#include <hip/hip_runtime.h>

#define DEV __device__ __forceinline__

typedef unsigned short bhalf;
typedef __attribute__((ext_vector_type(8))) short bf8v;
typedef __attribute__((ext_vector_type(4))) float f4;
typedef __attribute__((ext_vector_type(4))) unsigned short us4;

namespace {
constexpr int TPB = 256;
constexpr float ATT_SCALE = 0.08838834764831845f; // 1/sqrt(128)

// ---- workspace byte offsets ----
constexpr size_t O_PT  = 0;          // bf16 [640][64][256]  modalities, zero-pad rows
constexpr size_t O_WTS = 20971520;   // bf16 transposed weights (see W_* below)
constexpr size_t O_K1B = 21626880;   // bf16 [128][64][128]
constexpr size_t O_FW  = 23724032;   // bf16 fused weights: VQ[128][256], VK[128][256], VW[256][256]
constexpr size_t O_VQT = 27918336;   // bf16 [128][128][64]  (v1@arm_q)^T
constexpr size_t O_VKT = 30015488;   // bf16 [128][128][64]
constexpr size_t O_G   = 32112640;   // f32  [256][256]  arm_v@epw  (DEAD after wf2 -> reused as ST2 stats shards)
constexpr size_t O_VWT = 36306944;   // bf16 [128][256][64]  (vt@epw)^T
constexpr size_t O_Q2B = 40501248;   // bf16 [640][64][128]  (kv1 writes q1 here; s1ker overwrites with q2)
constexpr size_t O_K2B = 50987008;   // bf16 [640][64][128]
constexpr size_t O_W2T = 61472768;   // bf16 [640][256][64]
constexpr size_t O_FV  = 82444288;   // f32  [640][256]  node features X
constexpr size_t O_HWS = 83099648;   // f32  [3200][256]
constexpr size_t O_EDG = 86376448;   // f32  [3200][256]
constexpr size_t O_XA  = 89654272;
constexpr size_t O_XB  = 90309632;
constexpr size_t O_XU  = 90964992;
constexpr size_t O_XV  = 91620352;
constexpr size_t O_EE  = 92275712;   // (unused now; kept for layout stability)
constexpr size_t O_ET  = 95552512;
constexpr size_t O_XN  = 98829312;
// regions for MFMA GNN projections
constexpr size_t O_GWT = 99484672;   // bf16 10x[256][256] GNN weights Wt[n][k], order {A,B,U,V,E}xL
constexpr size_t O_CSE = 100795392;  // f32 [256] colsum of E1
constexpr size_t O_FVB = 100796416;  // bf16 [640][256] node features (kept in sync with FV)
constexpr size_t O_HWB = 101124096;  // bf16 [3200][256] raw HWS
constexpr size_t O_EDB = 102762496;  // bf16 [3200][256] edge features after L0

// WTS element offsets (bf16 elems), all stored as Wt[n][k=256]
constexpr size_t W_FAMQ = 0, W_FAMK = 32768, W_ARMQ = 65536, W_ARMK = 98304,
                 W_FAMV = 131072, W_ARMV = 196608, W_EPW = 262144;
// FW element offsets
constexpr size_t FW_VQ = 0, FW_VK = 32768, FW_VW = 65536;

// ST2 stat-shard float offsets (slot = xcd*32 + idx, xcd<8)
constexpr int ST_GS1 = 0, ST_GS2 = 256;
} // namespace

// ---------- helpers ----------

DEV bhalf f2b(float f) {
  unsigned u = __float_as_uint(f);
  return (bhalf)((u + 0x7FFFu + ((u >> 16) & 1u)) >> 16);
}

DEV f4 mfma16(bf8v a, bf8v b, f4 c) {
  return __builtin_amdgcn_mfma_f32_16x16x32_bf16(a, b, c, 0, 0, 0);
}

// fragment load: lane l reads row (r0 + (l&15)), 8 contiguous k at k0 + (l>>4)*8
DEV bf8v ldfrag(const bhalf* base, int r0, int k0, int S, int l) {
  return *reinterpret_cast<const bf8v*>(base + (size_t)(r0 + (l & 15)) * S + k0 + ((l >> 4) << 3));
}

// swizzled LDS fragment load: byte = row*stride + koffB, XOR'd with ((row&7)<<4)
DEV bf8v ldswz(const bhalf* base, int row, int koffB, int strideB) {
  int byte = row * strideB + koffB;
  byte ^= ((row & 7) << 4);
  return *reinterpret_cast<const bf8v*>(reinterpret_cast<const char*>(base) + byte);
}

// sum the 8 per-XCD shards of one stat
DEV float sumShards(const float* base, int idx) {
  float s = 0.f;
  #pragma unroll
  for (int x = 0; x < 8; ++x) s += base[x*32 + idx];
  return s;
}

// in-register row softmax: sv[nt][reg], row per reg spans cols nt*16+(l&15) across 16 lanes
DEV void regSoftmax(float sv[4][4]) {
  #pragma unroll
  for (int reg = 0; reg < 4; ++reg) {
    float m = fmaxf(fmaxf(sv[0][reg], sv[1][reg]), fmaxf(sv[2][reg], sv[3][reg]));
    #pragma unroll
    for (int off = 1; off <= 8; off <<= 1) m = fmaxf(m, __shfl_xor(m, off));
    float s = 0.f;
    #pragma unroll
    for (int nt = 0; nt < 4; ++nt) { float e = __expf(sv[nt][reg] - m); sv[nt][reg] = e; s += e; }
    #pragma unroll
    for (int off = 1; off <= 8; off <<= 1) s += __shfl_xor(s, off);
    float inv = 1.f / s;
    #pragma unroll
    for (int nt = 0; nt < 4; ++nt) sv[nt][reg] *= inv;
  }
}

// ga/gb already point at the per-XCD shard slot
DEV void reduce2Atomic(float a, float b, float* ga, float* gb, float* red) {
  #pragma unroll
  for (int off = 32; off; off >>= 1) { a += __shfl_down(a, off); b += __shfl_down(b, off); }
  if ((threadIdx.x & 63) == 0) { int w = threadIdx.x >> 6; red[w*2] = a; red[w*2+1] = b; }
  __syncthreads();
  if (threadIdx.x == 0) {
    atomicAdd(ga, red[0]+red[2]+red[4]+red[6]);
    atomicAdd(gb, red[1]+red[3]+red[5]+red[7]);
  }
  __syncthreads();
}

// ---------- prep kernel (wprep + modprep + G + GNN weight transpose + colsumE1) ----------

__global__ void __launch_bounds__(256) prepAll(const float* fq, const float* fk, const float* fv,
                                               const float* aq, const float* ak, const float* av,
                                               const float* ep, bhalf* WT,
                                               const float* af, const float* ef, const float* gf,
                                               const float* attf, const float* sf,
                                               bhalf* PT, float* FV, float* G,
                                               const float* A1, const float* B1, const float* U1,
                                               const float* V1, const float* E1,
                                               const float* A2, const float* B2, const float* U2,
                                               const float* V2, const float* E2,
                                               bhalf* GWT, float* CSE, bhalf* FVB) {
  __shared__ float lb[49*260];
  int tid = threadIdx.x;
  if (blockIdx.x < 1280) {
    // ---- wprep: transpose 7 weight matrices to bf16 Wt[n][256] ----
    int blk = blockIdx.x;
    const float* src; bhalf* dst; int N, n;
    if (blk < 512) {
      int m = blk >> 7; n = blk & 127; N = 128;
      src = (m==0)?fq:(m==1)?fk:(m==2)?aq:ak;
      dst = WT + (size_t)m*32768;
    } else {
      int r = blk - 512; int m = r >> 8; n = r & 255; N = 256;
      src = (m==0)?fv:(m==1)?av:ep;
      dst = WT + 131072 + (size_t)m*65536;
    }
    dst[(size_t)n*256 + tid] = f2b(src[(size_t)tid*N + n]);
  } else if (blockIdx.x < 1920) {
    // ---- modprep: per (bt,u) modality transpose + fv means ----
    int blk = blockIdx.x - 1280;
    int u = blk % 5, bt = blk / 5, b = bt >> 4, t = bt & 15;
    const float* src = (u==0)?af:(u==1)?ef:(u==2)?gf:(u==3)?attf:sf;
    src += ((size_t)b*256*16 + t)*49;
    for (int o = tid; o < 49*256; o += TPB) {
      int c = o / 49, p = o % 49;
      lb[p*260 + c] = src[(size_t)c*784 + p];
    }
    __syncthreads();
    bhalf* pt = PT + (size_t)blk*16384;
    for (int p = 0; p < 64; ++p)
      pt[p*256 + tid] = (p < 49) ? f2b(lb[p*260 + tid]) : (bhalf)0;
    float s = 0.f;
    for (int p = 0; p < 49; ++p) s += lb[p*260 + tid];
    float mval = s * (1.f/49.f);
    size_t idx = (((size_t)(b*5+u)*16) + t)*256 + tid;
    FV[idx] = mval;
    FVB[idx] = f2b(mval);
  } else if (blockIdx.x < 2176) {
    // ---- G = arm_v @ epw (f32), row c per block ----
    int c = blockIdx.x - 1920;
    const float* ar = av + (size_t)c*256;
    float acc = 0.f;
    for (int d = 0; d < 256; ++d)
      acc = fmaf(ar[d], ep[(size_t)d*256 + tid], acc);
    G[(size_t)c*256 + tid] = acc;
  } else if (blockIdx.x < 4736) {
    // ---- GNN weight transpose: 10 x [256][256] f32 -> bf16 Wt[n][256] ----
    int blk = blockIdx.x - 2176;
    int m = blk >> 8, n = blk & 255;
    const float* src = (m==0)?A1:(m==1)?B1:(m==2)?U1:(m==3)?V1:(m==4)?E1:
                       (m==5)?A2:(m==6)?B2:(m==7)?U2:(m==8)?V2:E2;
    GWT[(size_t)m*65536 + (size_t)n*256 + tid] = f2b(src[(size_t)tid*256 + n]);
  } else {
    // ---- colsum of E1 (for L0 edge BN-through-matmul) ----
    float s = 0.f;
    for (int c = 0; c < 256; ++c) s += E1[(size_t)c*256 + tid];
    CSE[tid] = s;
  }
}

// fused weights: W_VQ[n][k]=sum_c famv[k][c]*armq[c][n]; W_VK likewise; W_VW uses G.
__global__ void __launch_bounds__(256) wf2(const float* fv, const float* aq, const float* ak,
                                           const float* G, bhalf* FW) {
  int blk = blockIdx.x, tid = threadIdx.x;
  if (blk < 256) {
    int k = blk;
    if (tid < 128) {
      float a1 = 0.f, a2 = 0.f;
      for (int c = 0; c < 256; ++c) {
        float f = fv[(size_t)k*256 + c];
        a1 = fmaf(f, aq[(size_t)c*128 + tid], a1);
        a2 = fmaf(f, ak[(size_t)c*128 + tid], a2);
      }
      FW[FW_VQ + (size_t)tid*256 + k] = f2b(a1);
      FW[FW_VK + (size_t)tid*256 + k] = f2b(a2);
    }
  } else {
    int k = blk - 256;
    float a = 0.f;
    for (int c = 0; c < 256; ++c)
      a = fmaf(fv[(size_t)k*256 + c], G[(size_t)c*256 + tid], a);
    FW[FW_VW + (size_t)tid*256 + k] = f2b(a);
  }
}

// ---------- MFMA chain: everything from PT, B-operand STAGED IN LDS ----------
__global__ void __launch_bounds__(256, 4) kv1(const bhalf* PT, const bhalf* WT, const bhalf* FW,
                                              bhalf* K1B, bhalf* VQT, bhalf* VKT, bhalf* VWT,
                                              bhalf* Q2B) {
  __shared__ bhalf Wl[64*256];   // 32 KB, swizzled rows of 512 B
  int bt = blockIdx.x, part = blockIdx.y;
  int tid = threadIdx.x, w = tid >> 6, l = tid & 63;
  // resolve weight tile (64 rows from row nt0*16) and A source
  const bhalf* Wsrc; int nt0;
  const bhalf* A;
  if (part >= 10) {
    int u = (part - 10) >> 1;
    nt0 = ((part - 10) & 1) * 4;
    Wsrc = WT + W_FAMQ;
    A = PT + (size_t)(bt*5 + u)*16384;
  } else if (part < 2) {
    nt0 = part*4; Wsrc = WT + W_FAMK; A = PT + (size_t)bt*5*16384;
  } else if (part < 6) {
    nt0 = ((part - 2) & 1) * 4;
    Wsrc = FW + (((part - 2) >> 1) == 0 ? FW_VQ : FW_VK);
    A = PT + (size_t)bt*5*16384;
  } else {
    nt0 = (part - 6)*4; Wsrc = FW + FW_VW; A = PT + (size_t)bt*5*16384;
  }
  // A fragments (8 independent global loads, overlap with staging)
  bf8v a8[8];
  #pragma unroll
  for (int kt = 0; kt < 8; ++kt) a8[kt] = ldfrag(A, w*16, kt*32, 256, l);
  // stage weight tile: rows [nt0*16, nt0*16+64) x 256 cols, swizzled 512 B rows
  {
    const char* gw = reinterpret_cast<const char*>(Wsrc + (size_t)nt0*16*256);
    char* lw = reinterpret_cast<char*>(Wl);
    #pragma unroll
    for (int c = 0; c < 8; ++c) {
      int x = (c*256 + tid) << 4;                 // row = x>>9 (512 B rows)
      float4 val = *reinterpret_cast<const float4*>(gw + x);
      *reinterpret_cast<float4*>(lw + (x ^ (((x >> 9) & 7) << 4))) = val;
    }
  }
  __syncthreads();
  // compute 4 nt columns from LDS
  __builtin_amdgcn_s_setprio(1);
  f4 accs[4];
  #pragma unroll
  for (int nn = 0; nn < 4; ++nn) {
    f4 acc = {0.f,0.f,0.f,0.f};
    #pragma unroll
    for (int kt = 0; kt < 8; ++kt)
      acc = mfma16(a8[kt], ldswz(Wl, nn*16 + (l & 15), kt*64 + ((l >> 4) << 4), 512), acc);
    accs[nn] = acc;
  }
  __builtin_amdgcn_s_setprio(0);
  // stores per part type
  if (part >= 10) {
    int u = (part - 10) >> 1;
    bhalf* q1 = Q2B + (size_t)(bt*5 + u)*8192;
    #pragma unroll
    for (int nn = 0; nn < 4; ++nn) {
      int nt = nt0 + nn;
      #pragma unroll
      for (int reg = 0; reg < 4; ++reg) {
        int p = w*16 + ((l>>4)<<2) + reg;
        q1[(size_t)p*128 + nt*16 + (l&15)] = f2b(accs[nn][reg]);
      }
    }
  } else if (part < 2) {
    bhalf* dst = K1B + (size_t)bt*8192;
    #pragma unroll
    for (int nn = 0; nn < 4; ++nn) {
      int nt = nt0 + nn;
      #pragma unroll
      for (int reg = 0; reg < 4; ++reg) {
        int p = w*16 + ((l>>4)<<2) + reg;
        dst[(size_t)p*128 + nt*16 + (l&15)] = f2b(accs[nn][reg]);
      }
    }
  } else if (part < 6) {
    bhalf* o = ((((part - 2) >> 1) == 0) ? VQT : VKT) + (size_t)bt*8192;
    #pragma unroll
    for (int nn = 0; nn < 4; ++nn) {
      int n = (nt0 + nn)*16 + (l&15);
      int p0 = w*16 + ((l>>4)<<2);
      us4 pk = { f2b(accs[nn][0]), f2b(accs[nn][1]), f2b(accs[nn][2]), f2b(accs[nn][3]) };
      *reinterpret_cast<us4*>(o + (size_t)n*64 + p0) = pk;
    }
  } else {
    bhalf* ow = VWT + (size_t)bt*16384;
    #pragma unroll
    for (int nn = 0; nn < 4; ++nn) {
      int n = (nt0 + nn)*16 + (l&15);
      int p0 = w*16 + ((l>>4)<<2);
      us4 pk = { f2b(accs[nn][0]), f2b(accs[nn][1]), f2b(accs[nn][2]), f2b(accs[nn][3]) };
      *reinterpret_cast<us4*>(ow + (size_t)n*64 + p0) = pk;
    }
  }
}

// ---------- stage 1: FAM attention + ARM input projections (phase-1-free) ----------
__global__ void __launch_bounds__(256) s1ker(const bhalf* WT,
    const bhalf* K1B, const bhalf* VQT, const bhalf* VKT, const bhalf* VWT,
    bhalf* Q2B, bhalf* K2B, bhalf* W2T)
{
  __shared__ bhalf bufP[64*72];   // 9.2 KB, cross-wave P
  int orig = blockIdx.x;
  int blk = (orig & 7) * 80 + (orig >> 3);   // bijective XCD grouping
  int bt = blk / 5;
  int tid = threadIdx.x, w = tid >> 6, l = tid & 63;
  // phase 2: scores vs k1 (q1 fragments from Q2B), softmax in regs
  float sv[4][4];
  {
    const bhalf* Q1 = Q2B + (size_t)blk*8192;
    const bhalf* K1 = K1B + (size_t)bt*8192;
    bf8v aq[4];
    #pragma unroll
    for (int kt = 0; kt < 4; ++kt) aq[kt] = ldfrag(Q1, w*16, kt*32, 128, l);
    __builtin_amdgcn_s_setprio(1);
    #pragma unroll
    for (int nt = 0; nt < 4; ++nt) {
      f4 acc = {0.f,0.f,0.f,0.f};
      #pragma unroll
      for (int kt = 0; kt < 4; ++kt)
        acc = mfma16(aq[kt], ldfrag(K1, nt*16, kt*32, 128, l), acc);
      #pragma unroll
      for (int reg = 0; reg < 4; ++reg) sv[nt][reg] = acc[reg] * ATT_SCALE;
    }
    __builtin_amdgcn_s_setprio(0);
  }
  if ((l & 15) > 0) { sv[3][0] = -1e30f; sv[3][1] = -1e30f; sv[3][2] = -1e30f; sv[3][3] = -1e30f; }
  regSoftmax(sv);
  #pragma unroll
  for (int nt = 0; nt < 4; ++nt)
    #pragma unroll
    for (int reg = 0; reg < 4; ++reg)
      bufP[(w*16 + ((l>>4)<<2) + reg)*72 + nt*16 + (l&15)] = f2b(sv[nt][reg]);
  __syncthreads();   // bufP cross-wave
  // phase 3: column-split PVs. A-frags: all 4 row-groups of P.
  bf8v ap0[4], ap1[4];
  #pragma unroll
  for (int g = 0; g < 4; ++g) {
    ap0[g] = ldfrag(bufP, g*16, 0, 72, l);
    ap1[g] = ldfrag(bufP, g*16, 32, 72, l);
  }
  const bhalf* vq = VQT + (size_t)bt*8192;
  const bhalf* vk = VKT + (size_t)bt*8192;
  const bhalf* vw = VWT + (size_t)bt*16384;
  bhalf* q2 = Q2B + (size_t)blk*8192;
  bhalf* k2 = K2B + (size_t)blk*8192;
  bhalf* w2 = W2T + (size_t)blk*16384;
  __builtin_amdgcn_s_setprio(1);
  #pragma unroll
  for (int nn = 0; nn < 2; ++nn) {     // q2 cols nt = 2w+nn (overwrites q1 slot)
    int nt = w*2 + nn;
    bf8v b0 = ldfrag(vq, nt*16, 0, 64, l);
    bf8v b1 = ldfrag(vq, nt*16, 32, 64, l);
    f4 acc[4];
    #pragma unroll
    for (int g = 0; g < 4; ++g) {
      f4 z = {0.f,0.f,0.f,0.f};
      z = mfma16(ap0[g], b0, z);
      acc[g] = mfma16(ap1[g], b1, z);
    }
    int c = nt*16 + (l & 15);
    #pragma unroll
    for (int g = 0; g < 4; ++g)
      #pragma unroll
      for (int reg = 0; reg < 4; ++reg) {
        int p = g*16 + ((l>>4)<<2) + reg;
        q2[(size_t)p*128 + c] = (p < 49) ? f2b(acc[g][reg]) : (bhalf)0;
      }
  }
  #pragma unroll
  for (int nn = 0; nn < 2; ++nn) {     // k2 cols nt = 2w+nn
    int nt = w*2 + nn;
    bf8v b0 = ldfrag(vk, nt*16, 0, 64, l);
    bf8v b1 = ldfrag(vk, nt*16, 32, 64, l);
    f4 acc[4];
    #pragma unroll
    for (int g = 0; g < 4; ++g) {
      f4 z = {0.f,0.f,0.f,0.f};
      z = mfma16(ap0[g], b0, z);
      acc[g] = mfma16(ap1[g], b1, z);
    }
    int c = nt*16 + (l & 15);
    #pragma unroll
    for (int g = 0; g < 4; ++g)
      #pragma unroll
      for (int reg = 0; reg < 4; ++reg) {
        int p = g*16 + ((l>>4)<<2) + reg;
        k2[(size_t)p*128 + c] = (p < 49) ? f2b(acc[g][reg]) : (bhalf)0;
      }
  }
  #pragma unroll
  for (int nn = 0; nn < 4; ++nn) {     // w2t cols nt = 4w+nn, PACKED transposed store
    int nt = w*4 + nn;
    bf8v b0 = ldfrag(vw, nt*16, 0, 64, l);
    bf8v b1 = ldfrag(vw, nt*16, 32, 64, l);
    f4 acc[4];
    #pragma unroll
    for (int g = 0; g < 4; ++g) {
      f4 z = {0.f,0.f,0.f,0.f};
      z = mfma16(ap0[g], b0, z);
      acc[g] = mfma16(ap1[g], b1, z);
    }
    int c = nt*16 + (l & 15);
    int p0 = (l >> 4) << 2;
    #pragma unroll
    for (int g = 0; g < 4; ++g) {
      int pb = g*16 + p0;
      us4 pk = { (bhalf)((pb+0 < 49) ? f2b(acc[g][0]) : 0),
                 (bhalf)((pb+1 < 49) ? f2b(acc[g][1]) : 0),
                 (bhalf)((pb+2 < 49) ? f2b(acc[g][2]) : 0),
                 (bhalf)((pb+3 < 49) ? f2b(acc[g][3]) : 0) };
      *reinterpret_cast<us4*>(w2 + (size_t)c*64 + pb) = pk;
    }
  }
  __builtin_amdgcn_s_setprio(0);
}

// ---------- stage 2: ARM attention + edge stats (column-split PV, V in registers) ----------
__global__ void __launch_bounds__(256) s2ker(const bhalf* Q2B, const bhalf* K2B, const bhalf* W2T,
    const float* epb, float* hws, bhalf* hwsb, float* gs1, float* gs2)
{
  __shared__ bhalf Kl[64*128];    // 16 KB, swizzled rows of 256 B
  __shared__ bhalf bufP[64*72];   // 9 KB, full P (cross-wave)
  __shared__ float redH[256];     // 1 KB, per-wave disjoint columns
  __shared__ float redS[8];
  int orig = blockIdx.x;
  int blk = (orig & 7) * 400 + (orig >> 3);   // 3200 = 8*400, bijective XCD grouping
  int e = blk % 25, bt = blk / 25, b = bt >> 4, t = bt & 15;
  int i = e / 5, j = e % 5;
  int tid = threadIdx.x, w = tid >> 6, l = tid & 63;
  const bhalf* K = K2B + (size_t)(bt*5 + i)*8192;
  const bhalf* V = W2T + (size_t)(bt*5 + i)*16384;
  const bhalf* Q = Q2B + (size_t)(bt*5 + j)*8192;
  // prefetch Q fragments (independent of LDS staging)
  bf8v aq[4];
  #pragma unroll
  for (int kt = 0; kt < 4; ++kt) aq[kt] = ldfrag(Q, w*16, kt*32, 128, l);
  // ---- stage K (16 KB): coalesced global read, swizzled LDS write ----
  {
    const char* gk = reinterpret_cast<const char*>(K);
    char* lk = reinterpret_cast<char*>(Kl);
    #pragma unroll
    for (int c = 0; c < 4; ++c) {
      int x = (c*256 + tid) << 4;                 // K: row = x>>8 (256 B rows)
      float4 val = *reinterpret_cast<const float4*>(gk + x);
      *reinterpret_cast<float4*>(lk + (x ^ (((x >> 8) & 7) << 4))) = val;
    }
  }
  __syncthreads();
  // QK^T from LDS + in-register softmax
  float sv[4][4];
  __builtin_amdgcn_s_setprio(1);
  #pragma unroll
  for (int nt = 0; nt < 4; ++nt) {
    f4 acc = {0.f,0.f,0.f,0.f};
    #pragma unroll
    for (int kt = 0; kt < 4; ++kt)
      acc = mfma16(aq[kt], ldswz(Kl, nt*16 + (l & 15), kt*64 + ((l >> 4) << 4), 256), acc);
    #pragma unroll
    for (int reg = 0; reg < 4; ++reg) sv[nt][reg] = acc[reg] * ATT_SCALE;
  }
  __builtin_amdgcn_s_setprio(0);
  if ((l & 15) > 0) { sv[3][0] = -1e30f; sv[3][1] = -1e30f; sv[3][2] = -1e30f; sv[3][3] = -1e30f; }
  regSoftmax(sv);
  // write own P rows to bufP
  #pragma unroll
  for (int nt = 0; nt < 4; ++nt)
    #pragma unroll
    for (int reg = 0; reg < 4; ++reg)
      bufP[(w*16 + ((l>>4)<<2) + reg)*72 + nt*16 + (l&15)] = f2b(sv[nt][reg]);
  // V fragments for this wave's column slice (rows [w*64, w*64+64) of W2T tile)
  bf8v vf0[4], vf1[4];
  #pragma unroll
  for (int nn = 0; nn < 4; ++nn) {
    vf0[nn] = ldfrag(V, (w*4 + nn)*16, 0, 64, l);
    vf1[nn] = ldfrag(V, (w*4 + nn)*16, 32, 64, l);
  }
  __syncthreads();   // bufP complete (cross-wave read next)
  // A-fragments: all 4 row-groups of P
  bf8v ap0[4], ap1[4];
  #pragma unroll
  for (int g = 0; g < 4; ++g) {
    ap0[g] = ldfrag(bufP, g*16, 0, 72, l);
    ap1[g] = ldfrag(bufP, g*16, 32, 72, l);
  }
  float sqa = 0.f;
  __builtin_amdgcn_s_setprio(1);
  #pragma unroll
  for (int nn = 0; nn < 4; ++nn) {
    f4 acc[4];
    #pragma unroll
    for (int g = 0; g < 4; ++g) {
      f4 z = {0.f,0.f,0.f,0.f};
      z = mfma16(ap0[g], vf0[nn], z);
      acc[g] = mfma16(ap1[g], vf1[nn], z);
    }
    int c = ((w*4 + nn) << 4) + (l & 15);
    float bias = epb[c];
    float hw = 0.f;
    #pragma unroll
    for (int g = 0; g < 4; ++g) {
      #pragma unroll
      for (int reg = 0; reg < 4; ++reg) {
        int p = g*16 + ((l>>4)<<2) + reg;
        if (p < 49) { float v = acc[g][reg] + bias; hw += v; sqa += v*v; }
      }
    }
    hw += __shfl_xor(hw, 16);
    hw += __shfl_xor(hw, 32);
    if ((l >> 4) == 0) redH[c] = hw;   // per-wave disjoint c
  }
  __builtin_amdgcn_s_setprio(0);
  __syncthreads();
  float hwtot = redH[tid];
  size_t oidx = (((size_t)(b*25+e)*16) + t)*256 + tid;
  hws[oidx] = hwtot;
  hwsb[oidx] = f2b(hwtot);
  int slot = (orig & 7)*32 + e;
  reduce2Atomic(hwtot, sqa, gs1 + slot, gs2 + slot, redS);
}

// ---------- GNN back-half (verified fusions, per-XCD stat shards) ----------

// node MFMA projections: 160 blocks (m in {A,B,U,V}, 10 row-tiles x 4 col-tiles).
// kv1-pattern: 64-row tile, 32 KB swizzled LDS W staging, 4 waves x 16 rows.
__global__ void __launch_bounds__(256, 2) gnnProjN(const bhalf* Xb, const bhalf* GW,
    float* xA, float* xB, float* xU, float* xV) {
  __shared__ bhalf Wl[64*256];   // 32 KB
  int blk = blockIdx.x;
  int tid = threadIdx.x, w = tid >> 6, l = tid & 63;
  int m = blk / 40, rem = blk % 40, rt = rem >> 2, ct = rem & 3;
  const bhalf* A = Xb + (size_t)rt*64*256;
  const bhalf* Wsrc = GW + (size_t)m*65536;
  float* dst = (m==0)?xA:(m==1)?xB:(m==2)?xU:xV;
  bf8v a8[8];
  #pragma unroll
  for (int kt = 0; kt < 8; ++kt) a8[kt] = ldfrag(A, w*16, kt*32, 256, l);
  {
    const char* gw = reinterpret_cast<const char*>(Wsrc + (size_t)ct*64*256);
    char* lw = reinterpret_cast<char*>(Wl);
    #pragma unroll
    for (int c = 0; c < 8; ++c) {
      int x = (c*256 + tid) << 4;
      float4 val = *reinterpret_cast<const float4*>(gw + x);
      *reinterpret_cast<float4*>(lw + (x ^ (((x >> 9) & 7) << 4))) = val;
    }
  }
  __syncthreads();
  __builtin_amdgcn_s_setprio(1);
  f4 accs[4];
  #pragma unroll
  for (int nn = 0; nn < 4; ++nn) {
    f4 acc = {0.f,0.f,0.f,0.f};
    #pragma unroll
    for (int kt = 0; kt < 8; ++kt)
      acc = mfma16(a8[kt], ldswz(Wl, nn*16 + (l & 15), kt*64 + ((l >> 4) << 4), 512), acc);
    accs[nn] = acc;
  }
  __builtin_amdgcn_s_setprio(0);
  int p0 = w*16 + ((l>>4)<<2);
  size_t rbase = (size_t)rt*64 + p0;
  #pragma unroll
  for (int nn = 0; nn < 4; ++nn) {
    int n = ct*64 + nn*16 + (l&15);
    #pragma unroll
    for (int reg = 0; reg < 4; ++reg)
      dst[(rbase + reg)*256 + n] = accs[nn][reg];
  }
}

// edge MFMA projection FUSED with g2a: 200 blocks (50 row-tiles x 4 col-tiles).
// Epilogue: ET = xA[ni] + xB[nj] + (BN-fly edge proj), per-wave stats (e is
// wave-uniform: rows rt*64+w*16..+15 = one (b,e) t-group). eE buffer eliminated.
__global__ void __launch_bounds__(256, 2) gnnProjE(const bhalf* Eb, const bhalf* GW,
    const float* CSE, const float* gs1, const float* gs2, const float* gg, const float* gb,
    int bnfly, const float* xA, const float* xB, float* ET, float* es1, float* es2) {
  __shared__ bhalf Wl[64*256];   // 32 KB
  int blk = blockIdx.x;
  int tid = threadIdx.x, w = tid >> 6, l = tid & 63;
  int rt = blk >> 2, ct = blk & 3;
  const bhalf* A = Eb + (size_t)rt*64*256;
  bf8v a8[8];
  #pragma unroll
  for (int kt = 0; kt < 8; ++kt) a8[kt] = ldfrag(A, w*16, kt*32, 256, l);
  {
    const char* gw = reinterpret_cast<const char*>(GW + (size_t)ct*64*256);
    char* lw = reinterpret_cast<char*>(Wl);
    #pragma unroll
    for (int c = 0; c < 8; ++c) {
      int x = (c*256 + tid) << 4;
      float4 val = *reinterpret_cast<const float4*>(gw + x);
      *reinterpret_cast<float4*>(lw + (x ^ (((x >> 9) & 7) << 4))) = val;
    }
  }
  __syncthreads();
  __builtin_amdgcn_s_setprio(1);
  f4 accs[4];
  #pragma unroll
  for (int nn = 0; nn < 4; ++nn) {
    f4 acc = {0.f,0.f,0.f,0.f};
    #pragma unroll
    for (int kt = 0; kt < 8; ++kt)
      acc = mfma16(a8[kt], ldswz(Wl, nn*16 + (l & 15), kt*64 + ((l >> 4) << 4), 512), acc);
    accs[nn] = acc;
  }
  __builtin_amdgcn_s_setprio(0);
  // epilogue (uniform per wave; no branches inside the store loops)
  int be = rt*4 + w;              // (b*25+e)
  int b = be / 25, e = be % 25;
  int i = e / 5, j = e % 5;
  const float* xAr = xA + ((size_t)(b*5+i)*16)*256;
  const float* xBr = xB + ((size_t)(b*5+j)*16)*256;
  float scl = 1.f, ofs = 0.f;
  if (bnfly) {
    constexpr float invCnt = 1.f/1605632.f;
    float m = sumShards(gs1, e)*invCnt;
    float var = sumShards(gs2, e)*invCnt - m*m;
    float rstd = rsqrtf(var + 1e-5f);
    float g = gg[e]*rstd;
    scl = g * (1.f/49.f);
    ofs = gb[e] - g*m;
  }
  int t0 = (l>>4)<<2;
  float s1l = 0.f, s2l = 0.f;
  #pragma unroll
  for (int nn = 0; nn < 4; ++nn) {
    int n = ct*64 + nn*16 + (l&15);
    float cs = CSE[n] * ofs;      // ofs==0 for L1 -> cs==0
    #pragma unroll
    for (int reg = 0; reg < 4; ++reg) {
      int t = t0 + reg;
      float ve = fmaf(accs[nn][reg], scl, cs);
      float vfull = xAr[(size_t)t*256 + n] + xBr[(size_t)t*256 + n] + ve;
      ET[((size_t)be*16 + t)*256 + n] = vfull;
      s1l += vfull; s2l += vfull*vfull;
    }
  }
  #pragma unroll
  for (int off = 32; off; off >>= 1) { s1l += __shfl_down(s1l, off); s2l += __shfl_down(s2l, off); }
  if (l == 0) {
    int slot = (blk & 7)*32 + e;
    atomicAdd(es1 + slot, s1l);
    atomicAdd(es2 + slot, s2l);
  }
}

// fused g2b+g3a. Stats read as 8-shard sums; ns written to per-XCD shard.
// L0 additionally writes the bf16 copy of EDG (for the L1 MFMA projection).
__global__ void __launch_bounds__(256) g2bg3a(const float* ET, const float* HWS, const float* EDGin,
    float* EDGout, bhalf* EDGb, const float* xV, const float* xU, float* XN,
    const float* gs1, const float* gs2, const float* gemg, const float* gemb,
    const float* bg, const float* bb2, const float* es1, const float* es2,
    float* ns1, float* ns2, const float* efw, const float* efb, float* out, int layer) {
  __shared__ float red[8];
  int blk = blockIdx.x, tid = threadIdx.x;
  int b = blk / 80, i = (blk >> 4) % 5, t = blk & 15;
  constexpr float inv32k = 1.f/32768.f;
  constexpr float invCnt = 1.f/1605632.f;
  float ssum = 0.f, exv[5], xvv[5];
  #pragma unroll
  for (int j = 0; j < 5; ++j) {
    int e = i*5 + j;
    size_t ee = ((size_t)(b*25 + e)*16 + t)*256 + tid;
    float m = sumShards(es1, e)*inv32k;
    float var = sumShards(es2, e)*inv32k - m*m;
    float rstd = rsqrtf(var + 1e-5f);
    float v = bg[e]*((ET[ee]-m)*rstd) + bb2[e];
    if (v != v) v = 0.f;
    float base;
    if (layer == 0) {
      float gm = sumShards(gs1, e)*invCnt;
      float gvar = sumShards(gs2, e)*invCnt - gm*gm;
      float gr = rsqrtf(gvar + 1e-5f);
      base = gemg[e]*((HWS[ee]*(1.f/49.f) - gm)*gr) + gemb[e];
    } else {
      base = EDGin[ee];
    }
    float edg = base + fmaxf(v, 0.f);
    if (layer == 0) {
      EDGout[ee] = edg;
      EDGb[ee] = f2b(edg);
    } else {
      // fused finker edge part
      float vv = edg * efw[tid];
      #pragma unroll
      for (int off = 32; off; off >>= 1) vv += __shfl_down(vv, off);
      if ((tid & 63) == 0) red[tid >> 6] = vv;
      __syncthreads();
      if (tid == 0) out[640 + (size_t)(b*25 + e)*16 + t] = red[0]+red[1]+red[2]+red[3] + efb[0];
      __syncthreads();
    }
    float sg = 1.f/(1.f + __expf(-edg));
    exv[j] = __expf(sg);
    ssum += exv[j];
    xvv[j] = xV[((size_t)(b*5+j)*16 + t)*256 + tid];
  }
  float agg = 0.f;
  #pragma unroll
  for (int j = 0; j < 5; ++j) agg += exv[j]*xvv[j];
  agg *= 0.2f/ssum;
  float xn = xU[(size_t)blk*256 + tid] + agg;
  XN[(size_t)blk*256 + tid] = xn;
  int slot = (blk & 7)*32 + i;
  reduce2Atomic(xn, xn*xn, ns1 + slot, ns2 + slot, red);
}

// L0 node BN + residual relu (writes FV + bf16 copy for the next layer)
__global__ void __launch_bounds__(256) g3b(const float* XN, float* X, bhalf* Xb,
                                           const float* g, const float* bb,
                                           const float* s1, const float* s2, int mask) {
  int blk = blockIdx.x, tid = threadIdx.x;
  int i = (blk >> 4) % 5;
  size_t ni = (size_t)blk*256 + tid;
  constexpr float invCnt = 1.f/32768.f;
  float m = sumShards(s1, i)*invCnt;
  float var = sumShards(s2, i)*invCnt - m*m;
  float rstd = rsqrtf(var + 1e-5f);
  float v = g[i]*((XN[ni]-m)*rstd) + bb[i];
  if (mask && v != v) v = 0.f;
  float nv = fmaxf(X[ni] + v, 0.f);
  X[ni] = nv;
  Xb[ni] = f2b(nv);
}

// L1 node BN + residual relu fused with finker node part (FV never written)
__global__ void __launch_bounds__(256) g3bfin(const float* XN, const float* FV,
    const float* g, const float* bb, const float* s1, const float* s2,
    const float* sc, float* out) {
  __shared__ float red[12];
  int blk = blockIdx.x, tid = threadIdx.x;
  int i = (blk >> 4) % 5;
  size_t ni = (size_t)blk*256 + tid;
  constexpr float inv32k = 1.f/32768.f;
  float m = sumShards(s1, i)*inv32k;
  float var = sumShards(s2, i)*inv32k - m*m;
  float rstd = rsqrtf(var + 1e-5f);
  float v = g[i]*((XN[ni]-m)*rstd) + bb[i];   // L1: no NaN mask
  float x = fmaxf(FV[ni] + v, 0.f);
  float s = fmaxf(sc[i*256 + tid], 0.f);
  float xx = x*x, ss = s*s, xs = x*s;
  #pragma unroll
  for (int off = 32; off; off >>= 1) {
    xx += __shfl_down(xx, off); ss += __shfl_down(ss, off); xs += __shfl_down(xs, off);
  }
  if ((tid & 63) == 0) { int w = tid >> 6; red[w*3] = xx; red[w*3+1] = ss; red[w*3+2] = xs; }
  __syncthreads();
  if (tid == 0) {
    float sxx = red[0]+red[3]+red[6]+red[9];
    float sss = red[1]+red[4]+red[7]+red[10];
    float sxs = red[2]+red[5]+red[8]+red[11];
    float nx = fmaxf(sqrtf(sxx), 1e-12f);
    float ns = fmaxf(sqrtf(sss), 1e-12f);
    out[blk] = sxs / (nx * ns);
  }
}

// ---------- host ----------

extern "C" void kernel_launch(void* const* d_in, const int* in_sizes, int n_in,
                              void* d_out, int out_size, void* d_ws, size_t ws_size,
                              hipStream_t stream) {
  (void)in_sizes; (void)n_in; (void)out_size; (void)ws_size;
  const float* af    = (const float*)d_in[0];
  const float* ef    = (const float*)d_in[1];
  const float* gfm   = (const float*)d_in[2];
  const float* attf  = (const float*)d_in[3];
  const float* sfm   = (const float*)d_in[4];
  const float* fam_q = (const float*)d_in[5];
  const float* fam_k = (const float*)d_in[6];
  const float* fam_v = (const float*)d_in[7];
  const float* arm_q = (const float*)d_in[8];
  const float* arm_k = (const float*)d_in[9];
  const float* arm_v = (const float*)d_in[10];
  const float* epw   = (const float*)d_in[11];
  const float* epb   = (const float*)d_in[12];
  const float* gemg  = (const float*)d_in[13];
  const float* gemb  = (const float*)d_in[14];
  const float* Us[2]   = {(const float*)d_in[15], (const float*)d_in[20]};
  const float* Vs[2]   = {(const float*)d_in[16], (const float*)d_in[21]};
  const float* As[2]   = {(const float*)d_in[17], (const float*)d_in[22]};
  const float* Bs[2]   = {(const float*)d_in[18], (const float*)d_in[23]};
  const float* Es[2]   = {(const float*)d_in[19], (const float*)d_in[24]};
  const float* bnvg[2] = {(const float*)d_in[25], (const float*)d_in[29]};
  const float* bnvb[2] = {(const float*)d_in[26], (const float*)d_in[30]};
  const float* bneg[2] = {(const float*)d_in[27], (const float*)d_in[31]};
  const float* bneb[2] = {(const float*)d_in[28], (const float*)d_in[32]};
  const float* scp  = (const float*)d_in[33];
  const float* efw  = (const float*)d_in[34];
  const float* efb  = (const float*)d_in[35];

  char* ws = (char*)d_ws;
  bhalf* PT  = (bhalf*)(ws + O_PT);
  bhalf* WTS = (bhalf*)(ws + O_WTS);
  bhalf* K1B = (bhalf*)(ws + O_K1B);
  bhalf* FW  = (bhalf*)(ws + O_FW);
  bhalf* VQT = (bhalf*)(ws + O_VQT);
  bhalf* VKT = (bhalf*)(ws + O_VKT);
  float* G   = (float*)(ws + O_G);
  float* ST2 = (float*)(ws + O_G);    // stat shards reuse G's region (G dead after wf2)
  bhalf* VWT = (bhalf*)(ws + O_VWT);
  bhalf* Q2B = (bhalf*)(ws + O_Q2B);
  bhalf* K2B = (bhalf*)(ws + O_K2B);
  bhalf* W2T = (bhalf*)(ws + O_W2T);
  float* FV  = (float*)(ws + O_FV);
  float* HWS = (float*)(ws + O_HWS);
  float* EDG = (float*)(ws + O_EDG);
  float* XA  = (float*)(ws + O_XA);
  float* XB  = (float*)(ws + O_XB);
  float* XU  = (float*)(ws + O_XU);
  float* XV  = (float*)(ws + O_XV);
  float* ET  = (float*)(ws + O_ET);
  float* XN  = (float*)(ws + O_XN);
  bhalf* GWT = (bhalf*)(ws + O_GWT);
  float* CSE = (float*)(ws + O_CSE);
  bhalf* FVB = (bhalf*)(ws + O_FVB);
  bhalf* HWB = (bhalf*)(ws + O_HWB);
  bhalf* EDB = (bhalf*)(ws + O_EDB);

  prepAll<<<4737, TPB, 0, stream>>>(fam_q, fam_k, fam_v, arm_q, arm_k, arm_v, epw, WTS,
                                    af, ef, gfm, attf, sfm, PT, FV, G,
                                    As[0], Bs[0], Us[0], Vs[0], Es[0],
                                    As[1], Bs[1], Us[1], Vs[1], Es[1],
                                    GWT, CSE, FVB);
  wf2<<<512, TPB, 0, stream>>>(fam_v, arm_q, arm_k, G, FW);
  // G is dead now; zero the stat-shard region (2560 floats) in its place
  hipMemsetAsync(ST2, 0, 2560*sizeof(float), stream);
  // kv1 grid 128x20: parts 0-9 as before, parts 10-19 compute q1 -> Q2B
  kv1<<<dim3(128, 20), TPB, 0, stream>>>(PT, WTS, FW, K1B, VQT, VKT, VWT, Q2B);
  s1ker<<<640, TPB, 0, stream>>>(WTS, K1B, VQT, VKT, VWT, Q2B, K2B, W2T);
  s2ker<<<3200, TPB, 0, stream>>>(Q2B, K2B, W2T, epb, HWS, HWB, ST2 + ST_GS1, ST2 + ST_GS2);

  float* out = (float*)d_out;
  for (int L = 0; L < 2; ++L) {
    float* es1 = ST2 + 512 + L*1024;
    float* es2 = ST2 + 768 + L*1024;
    float* ns1 = ST2 + 1024 + L*1024;
    float* ns2 = ST2 + 1280 + L*1024;
    gnnProjN<<<160, TPB, 0, stream>>>(FVB, GWT + (size_t)L*5*65536, XA, XB, XU, XV);
    gnnProjE<<<200, TPB, 0, stream>>>((L == 0) ? HWB : EDB,
                                      GWT + (size_t)L*5*65536 + (size_t)4*65536, CSE,
                                      ST2 + ST_GS1, ST2 + ST_GS2, gemg, gemb, (L == 0) ? 1 : 0,
                                      XA, XB, ET, es1, es2);
    g2bg3a<<<640, TPB, 0, stream>>>(ET, HWS, EDG, EDG, EDB, XV, XU, XN,
                                    ST2 + ST_GS1, ST2 + ST_GS2, gemg, gemb,
                                    bneg[L], bneb[L], es1, es2, ns1, ns2,
                                    efw, efb, out, L);
    if (L == 0)
      g3b<<<640, TPB, 0, stream>>>(XN, FV, FVB, bnvg[0], bnvb[0], ns1, ns2, 1);
    else
      g3bfin<<<640, TPB, 0, stream>>>(XN, FV, bnvg[1], bnvb[1], ns1, ns2, scp, out);
  }
}